// Round 3
// baseline (1852.062 us; speedup 1.0000x reference)
//
#include <hip/hip_runtime.h>
#include <hip/hip_bf16.h>

// B=256, LATENT=64, HID=256, OUT=128, S=512. gates [i|f|g|o] -> 4H=1024.
//
// R8: 32 blocks x 8 batch rows x 1024 threads (16 waves -> 4 waves/SIMD).
// Wave w owns 16 h-cols [16w,16w+16) x 4 gates = 32 weight frags (1KB each):
//   g0 ks0..7 + g1 ks0..3 in VGPRs (12), g2 ks0..7 in LDS (8),
//   g1 ks4..7 + g3 ks0..7 streamed from L2 (12) - frag-contiguous wbf2.
// MFMA/wave/step = 32 (was 64). Valid C rows 0..7 live in quads 0,1; spread
// rows 2,3 (and 6,7) to quads 2,3 via 8x __shfl_xor(32) -> every lane does
// gate math for 2 h-elems (was 4). 4 waves/SIMD fill latency stalls that the
// old 2-wave lockstep exposed (ds_read ~120cy, L2 stream ~300cy, exp chains).
// hA: [2][16*STR], rows 8..15 zeroed once (MFMA A-tail), pad STR=264.
// hs written as scattered 2B stores (R6 proved stores are not the bottleneck).

typedef __bf16 v8bf __attribute__((ext_vector_type(8)));
typedef float  v4f  __attribute__((ext_vector_type(4)));

__device__ __forceinline__ float sigmoidf_(float x) {
    return __builtin_amdgcn_rcpf(1.0f + __expf(-x));
}
__device__ __forceinline__ float tanhf_(float x) {
    float ax = fabsf(x);
    float e  = __expf(-2.0f * ax);
    float t  = (1.0f - e) * __builtin_amdgcn_rcpf(1.0f + e);
    return copysignf(t, x);
}

// ---- wbf2 layout: frag FR = (c*4+g)*8+ks (c = h-col-tile 0..15), 1024 B each;
// lane l holds 16 B at FR*1024 + l*16 = w_hh[g*256+c*16+(l&15)][ks*32+(l>>4)*8 + 0..7]
__global__ void cvt_kernel(const float* __restrict__ w, uint4* __restrict__ o) {
    const int gg = blockIdx.x * 256 + threadIdx.x;    // 0..32767
    const int F = gg >> 6, l = gg & 63;
    const int c = F >> 5;                             // col-tile 0..15
    const int g4 = (F >> 3) & 3, ks = F & 7;
    const int row = g4 * 256 + c * 16 + (l & 15);
    const int col = ks * 32 + (l >> 4) * 8;
    const float4 a = *(const float4*)(w + row * 256 + col);
    const float4 b = *(const float4*)(w + row * 256 + col + 4);
    union { __hip_bfloat16 h[8]; uint4 u; } p;
    p.h[0] = __float2bfloat16(a.x); p.h[1] = __float2bfloat16(a.y);
    p.h[2] = __float2bfloat16(a.z); p.h[3] = __float2bfloat16(a.w);
    p.h[4] = __float2bfloat16(b.x); p.h[5] = __float2bfloat16(b.y);
    p.h[6] = __float2bfloat16(b.z); p.h[7] = __float2bfloat16(b.w);
    o[gg] = p.u;
}

constexpr int STR = 264;                 // hA row stride (bf16 elems), pad kills conflicts

__global__ __launch_bounds__(1024, 4) void lstm_main(
    const float* __restrict__ z,     const float* __restrict__ fc_w,
    const float* __restrict__ fc_b,  const float* __restrict__ w_ih,
    const float* __restrict__ b_ih,  const float* __restrict__ b_hh,
    const __hip_bfloat16* __restrict__ wbf2,
    __hip_bfloat16* __restrict__ hsb)           // = d_out viewed as bf16 [B*512][256]
{
    __shared__ __align__(16) unsigned char SM[16896 + 131072];
    __hip_bfloat16* hA = (__hip_bfloat16*)SM;             // [2][16*STR]
    unsigned char*  WL = SM + 16896;                      // weight LDS / prologue alias

    const int tid  = threadIdx.x;
    const int w    = tid >> 6;       // wave 0..15 = h-col-tile
    const int lane = tid & 63;
    const int l15  = lane & 15;
    const int quad = lane >> 4;
    const int b_base = blockIdx.x * 8;                    // 8 batch rows / block

    // ================= prologue (aliased LDS) =================
    float* h0f = (float*)WL;               // [8][256]   8 KB
    float* xps = (float*)(WL + 16384);     // [8][1024] 32 KB
    float* zt  = (float*)(WL + 81920);     // [8][64]    2 KB

    {   // z tile: 8 rows x 64; zero hA rows 8..15 (both buffers) once
        if (tid < 512) zt[tid] = z[b_base * 64 + tid];
        #pragma unroll
        for (int i = 0; i < 4; ++i) {
            const int idx = tid + i * 1024;               // 0..4095
            const int buf = idx >> 11;                    // 2048 per buffer
            const int row = 8 + ((idx >> 8) & 7);
            const int col = idx & 255;
            hA[buf * (16 * STR) + row * STR + col] = __float2bfloat16(0.0f);
        }
    }
    __syncthreads();

    {   // h0 = z @ fc_w.T + fc_b  (fp32 exact). thread: col=tid&255, 2 rows
        const int col = tid & 255;
        const int r0  = (tid >> 8) * 2;
        float a[2];
        const float bias = fc_b[col];
        a[0] = bias; a[1] = bias;
        for (int k = 0; k < 64; k += 4) {
            const float4 wv4 = *(const float4*)(fc_w + col * 64 + k);
            #pragma unroll
            for (int r = 0; r < 2; ++r) {
                const float4 h = *(const float4*)(zt + (r0 + r) * 64 + k);
                a[r] += wv4.x * h.x + wv4.y * h.y + wv4.z * h.z + wv4.w * h.w;
            }
        }
        #pragma unroll
        for (int r = 0; r < 2; ++r) {
            h0f[(r0 + r) * 256 + col] = a[r];
            hA[(r0 + r) * STR + col] = __float2bfloat16(a[r]);
        }
    }
    __syncthreads();

    {   // x_proj = h0 @ w_ih.T + (b_ih + b_hh)  (fp32 exact). thread: col tid
        const int c = tid;
        float a[8];
        const float bb = b_ih[c] + b_hh[c];
        #pragma unroll
        for (int r = 0; r < 8; ++r) a[r] = bb;
        for (int k = 0; k < 256; k += 4) {
            const float4 w0 = *(const float4*)(w_ih + c * 256 + k);
            #pragma unroll
            for (int r = 0; r < 8; ++r) {
                const float4 h = *(const float4*)(h0f + r * 256 + k);
                a[r] += w0.x * h.x + w0.y * h.y + w0.z * h.z + w0.w * h.w;
            }
        }
        #pragma unroll
        for (int r = 0; r < 8; ++r) xps[r * 1024 + c] = a[r];
    }
    __syncthreads();

    // gather xpr fragments (C-layout) before xps is overwritten.
    // rows (quad*4+r) >= 8 don't exist: read row&7 (finite filler; acc rows of
    // quads 2,3 are discarded by the spread below).
    v4f xpr[4];
    #pragma unroll
    for (int g = 0; g < 4; ++g)
        #pragma unroll
        for (int r = 0; r < 4; ++r)
            xpr[g][r] = xps[((quad * 4 + r) & 7) * 1024 + g * 256 + w * 16 + l15];
    __syncthreads();

    // ====== weights: 12 reg frags + 8 LDS frags; 12 streamed from L2 ======
    v8bf wreg[12];
    {
        const uint4* src = (const uint4*)wbf2;
        #pragma unroll
        for (int ks = 0; ks < 8; ++ks) {          // g0 -> reg 0..7
            union { uint4 u; v8bf v; } t; t.u = src[(w * 32 + ks) * 64 + lane];
            wreg[ks] = t.v;
        }
        #pragma unroll
        for (int ks = 0; ks < 4; ++ks) {          // g1 ks0..3 -> reg 8..11
            union { uint4 u; v8bf v; } t; t.u = src[(w * 32 + 8 + ks) * 64 + lane];
            wreg[8 + ks] = t.v;
        }
        uint4* wl = (uint4*)WL;
        #pragma unroll
        for (int ks = 0; ks < 8; ++ks)            // g2 -> LDS (own wave region)
            wl[(w * 8 + ks) * 64 + lane] = src[(w * 32 + 16 + ks) * 64 + lane];
    }

    // post-spread ownership: lane handles rows row0, row0+1 at col colw
    const int row0 = ((quad & 1) << 2) | ((quad >> 1) << 1);  // q0->0 q1->4 q2->2 q3->6
    const int colw = w * 16 + l15;
    float cst0 = 0.0f, cst1 = 0.0f;
    const __hip_bfloat16* sb1 = wbf2 + (size_t)(w * 32 + 8)  * 512 + lane * 8;  // g1 stream
    const __hip_bfloat16* sb3 = wbf2 + (size_t)(w * 32 + 24) * 512 + lane * 8;  // g3 stream
    const __hip_bfloat16* wlb = (const __hip_bfloat16*)WL + (size_t)(w * 8) * 512 + lane * 8;
    __hip_bfloat16* hs0 = hsb + (size_t)(b_base + row0) * 131072 + colw;
    __hip_bfloat16* hs1 = hs0 + 131072;

    __syncthreads();

    // ================= 512 recurrent steps =================
    for (int t = 0; t < 512; ++t) {
        const __hip_bfloat16* A = hA + (t & 1) * (16 * STR);
        v4f acc[4];

        #pragma unroll
        for (int ks = 0; ks < 8; ++ks) {
            const v8bf a = *(const v8bf*)(A + l15 * STR + ks * 32 + quad * 8);
            acc[0] = __builtin_amdgcn_mfma_f32_16x16x32_bf16(
                a, wreg[ks], (ks == 0) ? xpr[0] : acc[0], 0, 0, 0);
            const v8bf w1 = (ks < 4) ? wreg[8 + ks]
                                     : *(const v8bf*)(sb1 + ks * 512);
            acc[1] = __builtin_amdgcn_mfma_f32_16x16x32_bf16(
                a, w1, (ks == 0) ? xpr[1] : acc[1], 0, 0, 0);
            const v8bf w2 = *(const v8bf*)(wlb + ks * 512);
            acc[2] = __builtin_amdgcn_mfma_f32_16x16x32_bf16(
                a, w2, (ks == 0) ? xpr[2] : acc[2], 0, 0, 0);
            const v8bf w3 = *(const v8bf*)(sb3 + ks * 512);
            acc[3] = __builtin_amdgcn_mfma_f32_16x16x32_bf16(
                a, w3, (ks == 0) ? xpr[3] : acc[3], 0, 0, 0);
        }

        // spread: quads 2,3 take rows 2,3 / 6,7 from quads 0,1 (lane^32)
        float gv0[4], gv1[4];
        #pragma unroll
        for (int g = 0; g < 4; ++g) {
            const float s2 = __shfl_xor(acc[g][2], 32);
            const float s3 = __shfl_xor(acc[g][3], 32);
            gv0[g] = (lane < 32) ? acc[g][0] : s2;
            gv1[g] = (lane < 32) ? acc[g][1] : s3;
        }

        // gate math (2 h-elems/thread); h -> other LDS buffer + hs (bf16 rows)
        __hip_bfloat16* An = hA + ((t + 1) & 1) * (16 * STR);
        {
            const float iv = sigmoidf_(gv0[0]);
            const float fv = sigmoidf_(gv0[1]);
            const float gg = tanhf_  (gv0[2]);
            const float ov = sigmoidf_(gv0[3]);
            const float c  = fv * cst0 + iv * gg;
            cst0 = c;
            const __hip_bfloat16 hb = __float2bfloat16(ov * tanhf_(c));
            An[row0 * STR + colw] = hb;
            hs0[(size_t)t * 256] = hb;
        }
        {
            const float iv = sigmoidf_(gv1[0]);
            const float fv = sigmoidf_(gv1[1]);
            const float gg = tanhf_  (gv1[2]);
            const float ov = sigmoidf_(gv1[3]);
            const float c  = fv * cst1 + iv * gg;
            cst1 = c;
            const __hip_bfloat16 hb = __float2bfloat16(ov * tanhf_(c));
            An[(row0 + 1) * STR + colw] = hb;
            hs1[(size_t)t * 256] = hb;
        }
        __syncthreads();
    }
}

// ---- out-projection, in place over d_out: reads bf16 hs rows, writes fp32 out ----
__global__ __launch_bounds__(512, 2) void outproj_kernel(
    void* __restrict__ io, const float* __restrict__ out_w, const float* __restrict__ out_b)
{
    __shared__ __hip_bfloat16 tile[256 * STR];            // 256 rows x 264, 135168 B
    const __hip_bfloat16* hsb = (const __hip_bfloat16*)io;
    float* outp = (float*)io;

    const int tid  = threadIdx.x;
    const int wv   = tid >> 6;       // 0..7
    const int lane = tid & 63;
    const int l15  = lane & 15;
    const int quad = lane >> 4;
    const int m0   = blockIdx.x * 256;                    // (b,t) row base

    // stage 256x256 bf16 rows -> LDS (before any write: in-place safe)
    {
        const uint4* src = (const uint4*)(hsb + (size_t)m0 * 256);
        #pragma unroll
        for (int i = 0; i < 16; ++i) {
            const int cid = tid + i * 512;                // 0..8191 chunks of 16 B
            const int row = cid >> 5, c8 = (cid & 31) * 8;
            *(uint4*)&tile[row * STR + c8] = src[cid];
        }
    }
    __syncthreads();

    const int mbase = wv * 32;
    for (int nt = 0; nt < 8; ++nt) {
        union U8 { __hip_bfloat16 h[8]; v8bf v; };
        v8bf wo[8];
        #pragma unroll
        for (int ks = 0; ks < 8; ++ks) {
            const float* wr = out_w + (nt * 16 + l15) * 256 + ks * 32 + quad * 8;
            const float4 f0 = *(const float4*)wr;
            const float4 f1 = *(const float4*)(wr + 4);
            U8 u;
            u.h[0] = __float2bfloat16(f0.x); u.h[1] = __float2bfloat16(f0.y);
            u.h[2] = __float2bfloat16(f0.z); u.h[3] = __float2bfloat16(f0.w);
            u.h[4] = __float2bfloat16(f1.x); u.h[5] = __float2bfloat16(f1.y);
            u.h[6] = __float2bfloat16(f1.z); u.h[7] = __float2bfloat16(f1.w);
            wo[ks] = u.v;
        }
        const float ob = out_b[nt * 16 + l15];
        #pragma unroll
        for (int mt = 0; mt < 2; ++mt) {
            v4f oacc = { ob, ob, ob, ob };
            #pragma unroll
            for (int ks = 0; ks < 8; ++ks) {
                const v8bf a = *(const v8bf*)&tile[(mbase + mt * 16 + l15) * STR + ks * 32 + quad * 8];
                oacc = __builtin_amdgcn_mfma_f32_16x16x32_bf16(a, wo[ks], oacc, 0, 0, 0);
            }
            #pragma unroll
            for (int r = 0; r < 4; ++r)
                outp[(size_t)(m0 + mbase + mt * 16 + quad * 4 + r) * 128 + nt * 16 + l15] = oacc[r];
        }
    }
}

extern "C" void kernel_launch(void* const* d_in, const int* in_sizes, int n_in,
                              void* d_out, int out_size, void* d_ws, size_t ws_size,
                              hipStream_t stream) {
    (void)in_sizes; (void)n_in; (void)out_size; (void)ws_size;
    const float* z     = (const float*)d_in[0];
    const float* fc_w  = (const float*)d_in[1];
    const float* fc_b  = (const float*)d_in[2];
    const float* w_ih  = (const float*)d_in[3];
    const float* w_hh  = (const float*)d_in[4];
    const float* b_ih  = (const float*)d_in[5];
    const float* b_hh  = (const float*)d_in[6];
    const float* out_w = (const float*)d_in[7];
    const float* out_b = (const float*)d_in[8];

    __hip_bfloat16* wbf2 = (__hip_bfloat16*)d_ws;         // 512 KB swizzled w_hh

    hipLaunchKernelGGL(cvt_kernel, dim3(128), dim3(256), 0, stream, w_hh, (uint4*)wbf2);
    hipLaunchKernelGGL(lstm_main,  dim3(32),  dim3(1024), 0, stream,
                       z, fc_w, fc_b, w_ih, b_ih, b_hh, wbf2, (__hip_bfloat16*)d_out);
    hipLaunchKernelGGL(outproj_kernel, dim3(512), dim3(512), 0, stream,
                       d_out, out_w, out_b);
}

// Round 4
// 1258.389 us; speedup vs baseline: 1.4718x; 1.4718x over previous
//
#include <hip/hip_runtime.h>
#include <hip/hip_bf16.h>

// B=256, LATENT=64, HID=256, OUT=128, S=512. gates [i|f|g|o] -> 4H=1024.
//
// R9: 64 blocks x 4 batch rows x 512 thr (8 waves, 2/SIMD, R7 register budget).
// Wave wv owns h-cols [32wv,32wv+32) (2 j-tiles) x 4 gates = 64 frags, placed
// as in R7: 36 VGPR + 17 LDS + 11 L2-stream (frag-contiguous wbf2).
// Valid C rows 0..3 live in quad 0 only. Two-round spread:
//   round A: 16x shfl_xor(32) -> jt1 rows to quads 2,3 half (as R7)
//   round B:  8x shfl_xor(16) -> rows {2,3} to odd quads
// -> every lane does gate math for 2 h-elems (was 4). Per-CU per-step cost:
// MFMA/A-reads/weight fetch unchanged, gate VALU halves, CUs 32->64.
// (R8 lesson: adding waves/CU duplicates the fixed per-wave work - LDS port
// doubled and it regressed 32%. Halving rows/block only cuts gate+store work.)
// hA: [2][16*STR] rows 4..15 zeroed once; STR=264 pad kills conflicts.

typedef __bf16 v8bf __attribute__((ext_vector_type(8)));
typedef float  v4f  __attribute__((ext_vector_type(4)));

__device__ __forceinline__ float sigmoidf_(float x) {
    return __builtin_amdgcn_rcpf(1.0f + __expf(-x));
}
__device__ __forceinline__ float tanhf_(float x) {
    float ax = fabsf(x);
    float e  = __expf(-2.0f * ax);
    float t  = (1.0f - e) * __builtin_amdgcn_rcpf(1.0f + e);
    return copysignf(t, x);
}

// ---- wbf2 layout: frag FR(wv,jt,g,ks) = ((wv*2+jt)*4+g)*8+ks, 1024 B each;
// lane l holds 16 B at FR*1024 + l*16 = w_hh[g*256+wv*32+jt*16+(l&15)][ks*32+(l>>4)*8 + 0..7]
__global__ void cvt_kernel(const float* __restrict__ w, uint4* __restrict__ o) {
    const int gg = blockIdx.x * 256 + threadIdx.x;    // 0..32767
    const int F = gg >> 6, l = gg & 63;
    const int wv = F >> 6, rem = F & 63;
    const int jt = rem >> 5, g4 = (rem >> 3) & 3, ks = rem & 7;
    const int row = g4 * 256 + wv * 32 + jt * 16 + (l & 15);
    const int col = ks * 32 + (l >> 4) * 8;
    const float4 a = *(const float4*)(w + row * 256 + col);
    const float4 b = *(const float4*)(w + row * 256 + col + 4);
    union { __hip_bfloat16 h[8]; uint4 u; } p;
    p.h[0] = __float2bfloat16(a.x); p.h[1] = __float2bfloat16(a.y);
    p.h[2] = __float2bfloat16(a.z); p.h[3] = __float2bfloat16(a.w);
    p.h[4] = __float2bfloat16(b.x); p.h[5] = __float2bfloat16(b.y);
    p.h[6] = __float2bfloat16(b.z); p.h[7] = __float2bfloat16(b.w);
    o[gg] = p.u;
}

constexpr int STR = 264;                 // hA row stride (bf16 elems), pad kills conflicts

// jt==1 weight source tables: kind 0=reg,1=lds,2=stream
__device__ constexpr int K1[4][8] = {
    {0,0,0,0, 1, 2,2,2},
    {1,1,1,1, 1, 1,1,1},
    {1,1,1,1, 1, 2,2,2},
    {1,1,1, 2,2, 2,2,2},
};
__device__ constexpr int X1[4][8] = {
    {32,33,34,35, 0,  0,1,2},
    { 1, 2, 3, 4, 5,  6,7,8},
    { 9,10,11,12,13,  3,4,5},
    {14,15,16, 6, 7,  8,9,10},
};
// LDS staging list: lidx -> (g,ks) for jt1
__device__ constexpr int SG[17] = {0, 1,1,1,1,1,1,1,1, 2,2,2,2,2, 3,3,3};
__device__ constexpr int SK[17] = {4, 0,1,2,3,4,5,6,7, 0,1,2,3,4, 0,1,2};

__global__ __launch_bounds__(512, 2) void lstm_main(
    const float* __restrict__ z,     const float* __restrict__ fc_w,
    const float* __restrict__ fc_b,  const float* __restrict__ w_ih,
    const float* __restrict__ b_ih,  const float* __restrict__ b_hh,
    const __hip_bfloat16* __restrict__ wbf2,
    __hip_bfloat16* __restrict__ hsb)           // = d_out viewed as bf16 [B*512][256]
{
    __shared__ __align__(16) unsigned char SM[16896 + 139264];
    __hip_bfloat16* hA = (__hip_bfloat16*)SM;             // [2][16*STR]
    unsigned char*  WL = SM + 16896;                      // weight LDS / prologue alias

    const int tid  = threadIdx.x;
    const int wv   = tid >> 6;       // 0..7
    const int lane = tid & 63;
    const int l15  = lane & 15;
    const int quad = lane >> 4;
    const int b_base = blockIdx.x * 4;                    // 4 batch rows / block

    // ================= prologue (aliased LDS) =================
    float* h0f = (float*)WL;               // [4][256]   4 KB used
    float* xps = (float*)(WL + 16384);     // [4][1024] 16 KB used
    float* zt  = (float*)(WL + 81920);     // [4][64]    1 KB used

    {   // z tile: 4 rows x 64
        if (tid < 256) zt[tid] = z[b_base * 64 + tid];
        // zero hA rows 4..15 (both buffers): MFMA A-tile tail stays 0 forever
        #pragma unroll
        for (int i = 0; i < 12; ++i) {
            const int idx = tid + i * 512;                // 0..6143
            const int buf = (idx >= 3072) ? 1 : 0;
            const int rem = idx - buf * 3072;             // 0..3071
            const int row = 4 + (rem >> 8);               // 4..15
            const int col = rem & 255;
            hA[buf * (16 * STR) + row * STR + col] = __float2bfloat16(0.0f);
        }
    }
    __syncthreads();

    {   // h0 = z @ fc_w.T + fc_b  (fp32 exact). thread: col=tid&255, 2 rows
        const int col = tid & 255;
        const int r0  = (tid >> 8) * 2;
        float a[2];
        const float bias = fc_b[col];
        a[0] = bias; a[1] = bias;
        for (int k = 0; k < 64; k += 4) {
            const float4 w = *(const float4*)(fc_w + col * 64 + k);
            #pragma unroll
            for (int r = 0; r < 2; ++r) {
                const float4 h = *(const float4*)(zt + (r0 + r) * 64 + k);
                a[r] += w.x * h.x + w.y * h.y + w.z * h.z + w.w * h.w;
            }
        }
        #pragma unroll
        for (int r = 0; r < 2; ++r) {
            h0f[(r0 + r) * 256 + col] = a[r];
            hA[(r0 + r) * STR + col] = __float2bfloat16(a[r]);
        }
    }
    __syncthreads();

    {   // x_proj = h0 @ w_ih.T + (b_ih + b_hh)  (fp32 exact). cols tid, tid+512
        const int c0 = tid, c1 = tid + 512;
        float a0[4], a1[4];
        const float bb0 = b_ih[c0] + b_hh[c0];
        const float bb1 = b_ih[c1] + b_hh[c1];
        #pragma unroll
        for (int r = 0; r < 4; ++r) { a0[r] = bb0; a1[r] = bb1; }
        for (int k = 0; k < 256; k += 4) {
            const float4 w0 = *(const float4*)(w_ih + c0 * 256 + k);
            const float4 w1 = *(const float4*)(w_ih + c1 * 256 + k);
            #pragma unroll
            for (int r = 0; r < 4; ++r) {
                const float4 h = *(const float4*)(h0f + r * 256 + k);
                a0[r] += w0.x * h.x + w0.y * h.y + w0.z * h.z + w0.w * h.w;
                a1[r] += w1.x * h.x + w1.y * h.y + w1.z * h.z + w1.w * h.w;
            }
        }
        #pragma unroll
        for (int r = 0; r < 4; ++r) {
            xps[r * 1024 + c0] = a0[r];
            xps[r * 1024 + c1] = a1[r];
        }
    }
    __syncthreads();

    // gather xpr fragments (C-layout) before xps is overwritten.
    // rows (quad*4+r) >= 4 don't exist: read row&3 (finite filler; only routed
    // valid rows are ever consumed by gate math).
    v4f xpr[2][4];
    #pragma unroll
    for (int jt = 0; jt < 2; ++jt)
        #pragma unroll
        for (int g = 0; g < 4; ++g)
            #pragma unroll
            for (int r = 0; r < 4; ++r)
                xpr[jt][g][r] = xps[((quad * 4 + r) & 3) * 1024 + g * 256 + wv * 32 + jt * 16 + l15];
    __syncthreads();

    // ====== weights: 36 reg frags + 17 LDS frags (stream 11 stay in L2) ======
    v8bf wreg[36];
    {
        const uint4* src = (const uint4*)wbf2;
        #pragma unroll
        for (int g = 0; g < 4; ++g)
            #pragma unroll
            for (int ks = 0; ks < 8; ++ks) {      // jt0 -> reg 0..31
                const int FR = wv * 64 + g * 8 + ks;
                union { uint4 u; v8bf v; } t; t.u = src[FR * 64 + lane];
                wreg[g * 8 + ks] = t.v;
            }
        #pragma unroll
        for (int ks = 0; ks < 4; ++ks) {          // (jt1,g0,ks0..3) -> reg 32..35
            const int FR = wv * 64 + 32 + ks;
            union { uint4 u; v8bf v; } t; t.u = src[FR * 64 + lane];
            wreg[32 + ks] = t.v;
        }
        uint4* wl = (uint4*)WL;
        #pragma unroll
        for (int i = 0; i < 17; ++i) {            // LDS frags
            const int FR = wv * 64 + 32 + SG[i] * 8 + SK[i];
            wl[(wv * 17 + i) * 64 + lane] = src[FR * 64 + lane];
        }
    }

    // post-spread ownership: lane handles rows rb2, rb2+1 at col mycol
    const int rb2   = (quad & 1) * 2;                     // even quads rows{0,1}, odd {2,3}
    const int mycol = wv * 32 + (quad >> 1) * 16 + l15;   // jt = quad>>1
    float cst0 = 0.0f, cst1 = 0.0f;
    const __hip_bfloat16* sbase = wbf2 + (size_t)(wv * 64 + 32) * 512 + lane * 8;
    const __hip_bfloat16* wlbase = (const __hip_bfloat16*)WL + (size_t)(wv * 17) * 512 + lane * 8;
    __hip_bfloat16* hs0 = hsb + (size_t)(b_base + rb2) * 131072 + mycol;
    __hip_bfloat16* hs1 = hs0 + 131072;

    __syncthreads();

    // ================= 512 recurrent steps =================
    for (int t = 0; t < 512; ++t) {
        const __hip_bfloat16* A = hA + (t & 1) * (16 * STR);
        v4f acc[2][4];

        #pragma unroll
        for (int ks = 0; ks < 8; ++ks) {
            const v8bf a = *(const v8bf*)(A + l15 * STR + ks * 32 + quad * 8);
            #pragma unroll
            for (int g = 0; g < 4; ++g) {
                // jt = 0 (always register-resident)
                acc[0][g] = __builtin_amdgcn_mfma_f32_16x16x32_bf16(
                    a, wreg[g * 8 + ks], (ks == 0) ? xpr[0][g] : acc[0][g], 0, 0, 0);
                // jt = 1 (reg / LDS / L2-stream per table)
                v8bf w;
                if (K1[g][ks] == 0)      w = wreg[X1[g][ks]];
                else if (K1[g][ks] == 1) w = *(const v8bf*)(wlbase + X1[g][ks] * 512);
                else                     w = *(const v8bf*)(sbase + (g * 8 + ks) * 512);
                acc[1][g] = __builtin_amdgcn_mfma_f32_16x16x32_bf16(
                    a, w, (ks == 0) ? xpr[1][g] : acc[1][g], 0, 0, 0);
            }
        }

        // spread round A: jt1 rows 0..3 -> upper half lanes (quads 2,3 region)
        float a1v[4][4];
        #pragma unroll
        for (int g = 0; g < 4; ++g)
            #pragma unroll
            for (int r = 0; r < 4; ++r) {
                const float s = __shfl_xor(acc[1][g][r], 32);
                a1v[g][r] = (lane < 32) ? acc[0][g][r] : s;
            }
        // spread round B: rows {2,3} -> odd quads (xor 16 pulls from even quad)
        const int odd = quad & 1;
        float gv0[4], gv1[4];
        #pragma unroll
        for (int g = 0; g < 4; ++g) {
            const float s2 = __shfl_xor(a1v[g][2], 16);
            const float s3 = __shfl_xor(a1v[g][3], 16);
            gv0[g] = odd ? s2 : a1v[g][0];
            gv1[g] = odd ? s3 : a1v[g][1];
        }

        // gate math (2 h-elems/thread); h -> other LDS buffer + hs (bf16 rows)
        __hip_bfloat16* An = hA + ((t + 1) & 1) * (16 * STR);
        {
            const float iv = sigmoidf_(gv0[0]);
            const float fv = sigmoidf_(gv0[1]);
            const float gg = tanhf_  (gv0[2]);
            const float ov = sigmoidf_(gv0[3]);
            const float c  = fv * cst0 + iv * gg;
            cst0 = c;
            const __hip_bfloat16 hb = __float2bfloat16(ov * tanhf_(c));
            An[rb2 * STR + mycol] = hb;
            hs0[(size_t)t * 256] = hb;
        }
        {
            const float iv = sigmoidf_(gv1[0]);
            const float fv = sigmoidf_(gv1[1]);
            const float gg = tanhf_  (gv1[2]);
            const float ov = sigmoidf_(gv1[3]);
            const float c  = fv * cst1 + iv * gg;
            cst1 = c;
            const __hip_bfloat16 hb = __float2bfloat16(ov * tanhf_(c));
            An[(rb2 + 1) * STR + mycol] = hb;
            hs1[(size_t)t * 256] = hb;
        }
        __syncthreads();
    }
}

// ---- out-projection, in place over d_out: reads bf16 hs rows, writes fp32 out ----
__global__ __launch_bounds__(512, 2) void outproj_kernel(
    void* __restrict__ io, const float* __restrict__ out_w, const float* __restrict__ out_b)
{
    __shared__ __hip_bfloat16 tile[256 * STR];            // 256 rows x 264, 135168 B
    const __hip_bfloat16* hsb = (const __hip_bfloat16*)io;
    float* outp = (float*)io;

    const int tid  = threadIdx.x;
    const int wv   = tid >> 6;       // 0..7
    const int lane = tid & 63;
    const int l15  = lane & 15;
    const int quad = lane >> 4;
    const int m0   = blockIdx.x * 256;                    // (b,t) row base

    // stage 256x256 bf16 rows -> LDS (before any write: in-place safe)
    {
        const uint4* src = (const uint4*)(hsb + (size_t)m0 * 256);
        #pragma unroll
        for (int i = 0; i < 16; ++i) {
            const int cid = tid + i * 512;                // 0..8191 chunks of 16 B
            const int row = cid >> 5, c8 = (cid & 31) * 8;
            *(uint4*)&tile[row * STR + c8] = src[cid];
        }
    }
    __syncthreads();

    const int mbase = wv * 32;
    for (int nt = 0; nt < 8; ++nt) {
        union U8 { __hip_bfloat16 h[8]; v8bf v; };
        v8bf wo[8];
        #pragma unroll
        for (int ks = 0; ks < 8; ++ks) {
            const float* wr = out_w + (nt * 16 + l15) * 256 + ks * 32 + quad * 8;
            const float4 f0 = *(const float4*)wr;
            const float4 f1 = *(const float4*)(wr + 4);
            U8 u;
            u.h[0] = __float2bfloat16(f0.x); u.h[1] = __float2bfloat16(f0.y);
            u.h[2] = __float2bfloat16(f0.z); u.h[3] = __float2bfloat16(f0.w);
            u.h[4] = __float2bfloat16(f1.x); u.h[5] = __float2bfloat16(f1.y);
            u.h[6] = __float2bfloat16(f1.z); u.h[7] = __float2bfloat16(f1.w);
            wo[ks] = u.v;
        }
        const float ob = out_b[nt * 16 + l15];
        #pragma unroll
        for (int mt = 0; mt < 2; ++mt) {
            v4f oacc = { ob, ob, ob, ob };
            #pragma unroll
            for (int ks = 0; ks < 8; ++ks) {
                const v8bf a = *(const v8bf*)&tile[(mbase + mt * 16 + l15) * STR + ks * 32 + quad * 8];
                oacc = __builtin_amdgcn_mfma_f32_16x16x32_bf16(a, wo[ks], oacc, 0, 0, 0);
            }
            #pragma unroll
            for (int r = 0; r < 4; ++r)
                outp[(size_t)(m0 + mbase + mt * 16 + quad * 4 + r) * 128 + nt * 16 + l15] = oacc[r];
        }
    }
}

extern "C" void kernel_launch(void* const* d_in, const int* in_sizes, int n_in,
                              void* d_out, int out_size, void* d_ws, size_t ws_size,
                              hipStream_t stream) {
    (void)in_sizes; (void)n_in; (void)out_size; (void)ws_size;
    const float* z     = (const float*)d_in[0];
    const float* fc_w  = (const float*)d_in[1];
    const float* fc_b  = (const float*)d_in[2];
    const float* w_ih  = (const float*)d_in[3];
    const float* w_hh  = (const float*)d_in[4];
    const float* b_ih  = (const float*)d_in[5];
    const float* b_hh  = (const float*)d_in[6];
    const float* out_w = (const float*)d_in[7];
    const float* out_b = (const float*)d_in[8];

    __hip_bfloat16* wbf2 = (__hip_bfloat16*)d_ws;         // 512 KB swizzled w_hh

    hipLaunchKernelGGL(cvt_kernel, dim3(128), dim3(256), 0, stream, w_hh, (uint4*)wbf2);
    hipLaunchKernelGGL(lstm_main,  dim3(64),  dim3(512), 0, stream,
                       z, fc_w, fc_b, w_ih, b_ih, b_hh, wbf2, (__hip_bfloat16*)d_out);
    hipLaunchKernelGGL(outproj_kernel, dim3(512), dim3(512), 0, stream,
                       d_out, out_w, out_b);
}

// Round 5
// 1145.403 us; speedup vs baseline: 1.6170x; 1.0986x over previous
//
#include <hip/hip_runtime.h>
#include <hip/hip_bf16.h>

// B=256, LATENT=64, HID=256, OUT=128, S=512. gates [i|f|g|o] -> 4H=1024.
//
// R10: 128 blocks x 2 batch rows x 512 thr (8 waves, 2/SIMD).
// Wave wv owns h-cols [32wv,32wv+32) (2 j-tiles) x 4 gates = 64 frags, placed
// as in R7/R9: 36 VGPR + 17 LDS + 11 L2-stream (frag-contiguous wbf2).
// Valid C rows {0,1} live in quad 0 regs 0,1. Two-round spread (12 shuffles):
//   round A: 8x shfl_xor(32) -> jt1 rows 0,1 to quads 2,3 half
//   round B: 4x shfl_xor(16) -> row 1 to odd quads
// -> every lane does gate math for exactly 1 h-elem (was 2). Per-CU per-step:
// MFMA/A-reads/weight fetch unchanged, gate+spread+store VALU halves, CUs
// 64->128. (Verified lever: R7->R9 same transform gave -12%.)
// hA: [2][16*STR] rows 2..15 zeroed once; STR=264 pad kills conflicts.
// (R8 lesson: adding waves/CU duplicates fixed per-wave work - regressed.)

typedef __bf16 v8bf __attribute__((ext_vector_type(8)));
typedef float  v4f  __attribute__((ext_vector_type(4)));

__device__ __forceinline__ float sigmoidf_(float x) {
    return __builtin_amdgcn_rcpf(1.0f + __expf(-x));
}
__device__ __forceinline__ float tanhf_(float x) {
    float ax = fabsf(x);
    float e  = __expf(-2.0f * ax);
    float t  = (1.0f - e) * __builtin_amdgcn_rcpf(1.0f + e);
    return copysignf(t, x);
}

// ---- wbf2 layout: frag FR(wv,jt,g,ks) = ((wv*2+jt)*4+g)*8+ks, 1024 B each;
// lane l holds 16 B at FR*1024 + l*16 = w_hh[g*256+wv*32+jt*16+(l&15)][ks*32+(l>>4)*8 + 0..7]
__global__ void cvt_kernel(const float* __restrict__ w, uint4* __restrict__ o) {
    const int gg = blockIdx.x * 256 + threadIdx.x;    // 0..32767
    const int F = gg >> 6, l = gg & 63;
    const int wv = F >> 6, rem = F & 63;
    const int jt = rem >> 5, g4 = (rem >> 3) & 3, ks = rem & 7;
    const int row = g4 * 256 + wv * 32 + jt * 16 + (l & 15);
    const int col = ks * 32 + (l >> 4) * 8;
    const float4 a = *(const float4*)(w + row * 256 + col);
    const float4 b = *(const float4*)(w + row * 256 + col + 4);
    union { __hip_bfloat16 h[8]; uint4 u; } p;
    p.h[0] = __float2bfloat16(a.x); p.h[1] = __float2bfloat16(a.y);
    p.h[2] = __float2bfloat16(a.z); p.h[3] = __float2bfloat16(a.w);
    p.h[4] = __float2bfloat16(b.x); p.h[5] = __float2bfloat16(b.y);
    p.h[6] = __float2bfloat16(b.z); p.h[7] = __float2bfloat16(b.w);
    o[gg] = p.u;
}

constexpr int STR = 264;                 // hA row stride (bf16 elems), pad kills conflicts

// jt==1 weight source tables: kind 0=reg,1=lds,2=stream
__device__ constexpr int K1[4][8] = {
    {0,0,0,0, 1, 2,2,2},
    {1,1,1,1, 1, 1,1,1},
    {1,1,1,1, 1, 2,2,2},
    {1,1,1, 2,2, 2,2,2},
};
__device__ constexpr int X1[4][8] = {
    {32,33,34,35, 0,  0,1,2},
    { 1, 2, 3, 4, 5,  6,7,8},
    { 9,10,11,12,13,  3,4,5},
    {14,15,16, 6, 7,  8,9,10},
};
// LDS staging list: lidx -> (g,ks) for jt1
__device__ constexpr int SG[17] = {0, 1,1,1,1,1,1,1,1, 2,2,2,2,2, 3,3,3};
__device__ constexpr int SK[17] = {4, 0,1,2,3,4,5,6,7, 0,1,2,3,4, 0,1,2};

__global__ __launch_bounds__(512, 2) void lstm_main(
    const float* __restrict__ z,     const float* __restrict__ fc_w,
    const float* __restrict__ fc_b,  const float* __restrict__ w_ih,
    const float* __restrict__ b_ih,  const float* __restrict__ b_hh,
    const __hip_bfloat16* __restrict__ wbf2,
    __hip_bfloat16* __restrict__ hsb)           // = d_out viewed as bf16 [B*512][256]
{
    __shared__ __align__(16) unsigned char SM[16896 + 139264];
    __hip_bfloat16* hA = (__hip_bfloat16*)SM;             // [2][16*STR]
    unsigned char*  WL = SM + 16896;                      // weight LDS / prologue alias

    const int tid  = threadIdx.x;
    const int wv   = tid >> 6;       // 0..7
    const int lane = tid & 63;
    const int l15  = lane & 15;
    const int quad = lane >> 4;
    const int b_base = blockIdx.x * 2;                    // 2 batch rows / block

    // ================= prologue (aliased LDS) =================
    float* h0f = (float*)WL;               // [2][256]   2 KB used
    float* xps = (float*)(WL + 16384);     // [2][1024]  8 KB used
    float* zt  = (float*)(WL + 81920);     // [2][64]   0.5 KB used

    {   // z tile: 2 rows x 64
        if (tid < 128) zt[tid] = z[b_base * 64 + tid];
        // zero hA rows 2..15 (both buffers): MFMA A-tile tail stays 0 forever
        #pragma unroll
        for (int i = 0; i < 14; ++i) {
            const int idx = tid + i * 512;                // 0..7167
            const int buf = (idx >= 3584) ? 1 : 0;
            const int rem = idx - buf * 3584;             // 0..3583
            const int row = 2 + (rem >> 8);               // 2..15
            const int col = rem & 255;
            hA[buf * (16 * STR) + row * STR + col] = __float2bfloat16(0.0f);
        }
    }
    __syncthreads();

    {   // h0 = z @ fc_w.T + fc_b  (fp32 exact). thread: col=tid&255, row=tid>>8
        const int col = tid & 255;
        const int r   = tid >> 8;                         // 0 or 1
        float a = fc_b[col];
        for (int k = 0; k < 64; k += 4) {
            const float4 w = *(const float4*)(fc_w + col * 64 + k);
            const float4 h = *(const float4*)(zt + r * 64 + k);
            a += w.x * h.x + w.y * h.y + w.z * h.z + w.w * h.w;
        }
        h0f[r * 256 + col] = a;
        hA[r * STR + col] = __float2bfloat16(a);
    }
    __syncthreads();

    {   // x_proj = h0 @ w_ih.T + (b_ih + b_hh)  (fp32 exact). cols tid, tid+512
        const int c0 = tid, c1 = tid + 512;
        float a0[2], a1[2];
        const float bb0 = b_ih[c0] + b_hh[c0];
        const float bb1 = b_ih[c1] + b_hh[c1];
        a0[0] = bb0; a0[1] = bb0; a1[0] = bb1; a1[1] = bb1;
        for (int k = 0; k < 256; k += 4) {
            const float4 w0 = *(const float4*)(w_ih + c0 * 256 + k);
            const float4 w1 = *(const float4*)(w_ih + c1 * 256 + k);
            #pragma unroll
            for (int r = 0; r < 2; ++r) {
                const float4 h = *(const float4*)(h0f + r * 256 + k);
                a0[r] += w0.x * h.x + w0.y * h.y + w0.z * h.z + w0.w * h.w;
                a1[r] += w1.x * h.x + w1.y * h.y + w1.z * h.z + w1.w * h.w;
            }
        }
        #pragma unroll
        for (int r = 0; r < 2; ++r) {
            xps[r * 1024 + c0] = a0[r];
            xps[r * 1024 + c1] = a1[r];
        }
    }
    __syncthreads();

    // gather xpr fragments (C-layout) before xps is overwritten.
    // rows (quad*4+r) >= 2 don't exist: read row&1 (finite filler; only routed
    // valid rows are ever consumed by gate math).
    v4f xpr[2][4];
    #pragma unroll
    for (int jt = 0; jt < 2; ++jt)
        #pragma unroll
        for (int g = 0; g < 4; ++g)
            #pragma unroll
            for (int r = 0; r < 4; ++r)
                xpr[jt][g][r] = xps[((quad * 4 + r) & 1) * 1024 + g * 256 + wv * 32 + jt * 16 + l15];
    __syncthreads();

    // ====== weights: 36 reg frags + 17 LDS frags (stream 11 stay in L2) ======
    v8bf wreg[36];
    {
        const uint4* src = (const uint4*)wbf2;
        #pragma unroll
        for (int g = 0; g < 4; ++g)
            #pragma unroll
            for (int ks = 0; ks < 8; ++ks) {      // jt0 -> reg 0..31
                const int FR = wv * 64 + g * 8 + ks;
                union { uint4 u; v8bf v; } t; t.u = src[FR * 64 + lane];
                wreg[g * 8 + ks] = t.v;
            }
        #pragma unroll
        for (int ks = 0; ks < 4; ++ks) {          // (jt1,g0,ks0..3) -> reg 32..35
            const int FR = wv * 64 + 32 + ks;
            union { uint4 u; v8bf v; } t; t.u = src[FR * 64 + lane];
            wreg[32 + ks] = t.v;
        }
        uint4* wl = (uint4*)WL;
        #pragma unroll
        for (int i = 0; i < 17; ++i) {            // LDS frags
            const int FR = wv * 64 + 32 + SG[i] * 8 + SK[i];
            wl[(wv * 17 + i) * 64 + lane] = src[FR * 64 + lane];
        }
    }

    // post-spread ownership: lane handles exactly 1 h-elem (row rb, col mycol)
    const int rb    = quad & 1;                           // even quads row 0, odd row 1
    const int mycol = wv * 32 + (quad >> 1) * 16 + l15;   // jt = quad>>1
    float cst = 0.0f;
    const __hip_bfloat16* sbase = wbf2 + (size_t)(wv * 64 + 32) * 512 + lane * 8;
    const __hip_bfloat16* wlbase = (const __hip_bfloat16*)WL + (size_t)(wv * 17) * 512 + lane * 8;
    __hip_bfloat16* hsp = hsb + (size_t)(b_base + rb) * 131072 + mycol;

    __syncthreads();

    // ================= 512 recurrent steps =================
    for (int t = 0; t < 512; ++t) {
        const __hip_bfloat16* A = hA + (t & 1) * (16 * STR);
        v4f acc[2][4];

        #pragma unroll
        for (int ks = 0; ks < 8; ++ks) {
            const v8bf a = *(const v8bf*)(A + l15 * STR + ks * 32 + quad * 8);
            #pragma unroll
            for (int g = 0; g < 4; ++g) {
                // jt = 0 (always register-resident)
                acc[0][g] = __builtin_amdgcn_mfma_f32_16x16x32_bf16(
                    a, wreg[g * 8 + ks], (ks == 0) ? xpr[0][g] : acc[0][g], 0, 0, 0);
                // jt = 1 (reg / LDS / L2-stream per table)
                v8bf w;
                if (K1[g][ks] == 0)      w = wreg[X1[g][ks]];
                else if (K1[g][ks] == 1) w = *(const v8bf*)(wlbase + X1[g][ks] * 512);
                else                     w = *(const v8bf*)(sbase + (g * 8 + ks) * 512);
                acc[1][g] = __builtin_amdgcn_mfma_f32_16x16x32_bf16(
                    a, w, (ks == 0) ? xpr[1][g] : acc[1][g], 0, 0, 0);
            }
        }

        // spread (12 shuffles): valid C rows {0,1} live in quad 0 regs 0,1.
        // round A: jt1 rows 0,1 -> upper half (xor 32); round B: row 1 -> odd
        // quads (xor 16). Lane ends with its (rb, jt) element in gv[g].
        float gv[4];
        #pragma unroll
        for (int g = 0; g < 4; ++g) {
            const float sA0 = __shfl_xor(acc[1][g][0], 32);
            const float sA1 = __shfl_xor(acc[1][g][1], 32);
            const float a0  = (lane < 32) ? acc[0][g][0] : sA0;
            const float a1  = (lane < 32) ? acc[0][g][1] : sA1;
            const float s1  = __shfl_xor(a1, 16);
            gv[g] = (quad & 1) ? s1 : a0;
        }

        // gate math (1 h-elem/thread); h -> other LDS buffer + hs (bf16 rows)
        __hip_bfloat16* An = hA + ((t + 1) & 1) * (16 * STR);
        {
            const float iv = sigmoidf_(gv[0]);
            const float fv = sigmoidf_(gv[1]);
            const float gg = tanhf_  (gv[2]);
            const float ov = sigmoidf_(gv[3]);
            const float c  = fv * cst + iv * gg;
            cst = c;
            const __hip_bfloat16 hb = __float2bfloat16(ov * tanhf_(c));
            An[rb * STR + mycol] = hb;
            hsp[(size_t)t * 256] = hb;
        }
        __syncthreads();
    }
}

// ---- out-projection, in place over d_out: reads bf16 hs rows, writes fp32 out ----
__global__ __launch_bounds__(512, 2) void outproj_kernel(
    void* __restrict__ io, const float* __restrict__ out_w, const float* __restrict__ out_b)
{
    __shared__ __hip_bfloat16 tile[256 * STR];            // 256 rows x 264, 135168 B
    const __hip_bfloat16* hsb = (const __hip_bfloat16*)io;
    float* outp = (float*)io;

    const int tid  = threadIdx.x;
    const int wv   = tid >> 6;       // 0..7
    const int lane = tid & 63;
    const int l15  = lane & 15;
    const int quad = lane >> 4;
    const int m0   = blockIdx.x * 256;                    // (b,t) row base

    // stage 256x256 bf16 rows -> LDS (before any write: in-place safe)
    {
        const uint4* src = (const uint4*)(hsb + (size_t)m0 * 256);
        #pragma unroll
        for (int i = 0; i < 16; ++i) {
            const int cid = tid + i * 512;                // 0..8191 chunks of 16 B
            const int row = cid >> 5, c8 = (cid & 31) * 8;
            *(uint4*)&tile[row * STR + c8] = src[cid];
        }
    }
    __syncthreads();

    const int mbase = wv * 32;
    for (int nt = 0; nt < 8; ++nt) {
        union U8 { __hip_bfloat16 h[8]; v8bf v; };
        v8bf wo[8];
        #pragma unroll
        for (int ks = 0; ks < 8; ++ks) {
            const float* wr = out_w + (nt * 16 + l15) * 256 + ks * 32 + quad * 8;
            const float4 f0 = *(const float4*)wr;
            const float4 f1 = *(const float4*)(wr + 4);
            U8 u;
            u.h[0] = __float2bfloat16(f0.x); u.h[1] = __float2bfloat16(f0.y);
            u.h[2] = __float2bfloat16(f0.z); u.h[3] = __float2bfloat16(f0.w);
            u.h[4] = __float2bfloat16(f1.x); u.h[5] = __float2bfloat16(f1.y);
            u.h[6] = __float2bfloat16(f1.z); u.h[7] = __float2bfloat16(f1.w);
            wo[ks] = u.v;
        }
        const float ob = out_b[nt * 16 + l15];
        #pragma unroll
        for (int mt = 0; mt < 2; ++mt) {
            v4f oacc = { ob, ob, ob, ob };
            #pragma unroll
            for (int ks = 0; ks < 8; ++ks) {
                const v8bf a = *(const v8bf*)&tile[(mbase + mt * 16 + l15) * STR + ks * 32 + quad * 8];
                oacc = __builtin_amdgcn_mfma_f32_16x16x32_bf16(a, wo[ks], oacc, 0, 0, 0);
            }
            #pragma unroll
            for (int r = 0; r < 4; ++r)
                outp[(size_t)(m0 + mbase + mt * 16 + quad * 4 + r) * 128 + nt * 16 + l15] = oacc[r];
        }
    }
}

extern "C" void kernel_launch(void* const* d_in, const int* in_sizes, int n_in,
                              void* d_out, int out_size, void* d_ws, size_t ws_size,
                              hipStream_t stream) {
    (void)in_sizes; (void)n_in; (void)out_size; (void)ws_size;
    const float* z     = (const float*)d_in[0];
    const float* fc_w  = (const float*)d_in[1];
    const float* fc_b  = (const float*)d_in[2];
    const float* w_ih  = (const float*)d_in[3];
    const float* w_hh  = (const float*)d_in[4];
    const float* b_ih  = (const float*)d_in[5];
    const float* b_hh  = (const float*)d_in[6];
    const float* out_w = (const float*)d_in[7];
    const float* out_b = (const float*)d_in[8];

    __hip_bfloat16* wbf2 = (__hip_bfloat16*)d_ws;         // 512 KB swizzled w_hh

    hipLaunchKernelGGL(cvt_kernel, dim3(128), dim3(256), 0, stream, w_hh, (uint4*)wbf2);
    hipLaunchKernelGGL(lstm_main,  dim3(128), dim3(512), 0, stream,
                       z, fc_w, fc_b, w_ih, b_ih, b_hh, wbf2, (__hip_bfloat16*)d_out);
    hipLaunchKernelGGL(outproj_kernel, dim3(512), dim3(512), 0, stream,
                       d_out, out_w, out_b);
}